// Round 1
// baseline (19.580 us; speedup 1.0000x reference)
//
#include <hip/hip_runtime.h>
#include <math.h>

// Problem constants (from reference): M,N = 2048, K = 64, O = 128
#define PM 2048
#define PN 2048
#define PK 64
#define PO 128
#define NWAVES 4
#define CHUNK (PN / NWAVES) /* 512 */

__global__ __launch_bounds__(256) void pna_fused_kernel(
    const float* __restrict__ adj,   // (M,N)
    const float* __restrict__ feat,  // (N,K)
    const float* __restrict__ W,     // (4K,O)
    const float* __restrict__ b,     // (O,)
    float* __restrict__ out)         // (M,O)
{
    __shared__ float red_s [NWAVES][PK];
    __shared__ float red_s2[NWAVES][PK];
    __shared__ float red_mx[NWAVES][PK];
    __shared__ float red_mn[NWAVES][PK];
    __shared__ int   red_cnt[NWAVES];
    __shared__ float comb[4 * PK];

    const int m    = blockIdx.x;
    const int t    = threadIdx.x;
    const int w    = t >> 6;   // wave id 0..3
    const int lane = t & 63;   // lane doubles as k index (K==64)

    const float* adjrow = adj + (size_t)m * PN;

    float s  = 0.0f, s2 = 0.0f;
    float mx = -INFINITY, mn = INFINITY;
    int   cntw = 0;

    const int base0 = w * CHUNK;
    // Scan this wave's contiguous chunk of the adjacency row.
    // Each iteration: 64 lanes read 64 consecutive adj entries (coalesced),
    // ballot the nonzeros, then walk set bits in ascending order
    // (deterministic across replays, no atomics).
    #pragma unroll 2
    for (int it = 0; it < CHUNK / 64; ++it) {
        const int n0 = base0 + it * 64;
        const float a = adjrow[n0 + lane];
        unsigned long long mask = __ballot(a != 0.0f);
        cntw += (int)__popcll(mask);
        while (mask) {
            const int bpos = __builtin_ctzll(mask);
            mask &= (mask - 1);
            const float av = __shfl(a, bpos, 64);
            const int   n  = n0 + bpos;
            // lane == k: one coalesced 256B row of features per neighbor
            const float p = av * feat[(size_t)n * PK + lane];
            s  += p;
            s2 += p * p;
            mx = fmaxf(mx, p);
            mn = fminf(mn, p);
        }
    }

    red_s [w][lane] = s;
    red_s2[w][lane] = s2;
    red_mx[w][lane] = mx;
    red_mn[w][lane] = mn;
    if (lane == 0) red_cnt[w] = cntw;
    __syncthreads();

    // Cross-wave reduction + statistics, one thread per k.
    if (t < PK) {
        const int k = t;
        float S = 0.0f, S2 = 0.0f;
        float MX = -INFINITY, MN = INFINITY;
        int   C = 0;
        #pragma unroll
        for (int ww = 0; ww < NWAVES; ++ww) {
            S  += red_s [ww][k];
            S2 += red_s2[ww][k];
            MX = fmaxf(MX, red_mx[ww][k]);
            MN = fminf(MN, red_mn[ww][k]);
            C  += red_cnt[ww];
        }
        const float mean = S / (float)PN;
        float var = (S2 - S * S / (float)PN) / (float)(PN - 1);
        var = fmaxf(var, 0.0f);
        const float sd = sqrtf(var);
        if (C < PN) {            // at least one zero product in the row
            MX = fmaxf(MX, 0.0f);
            MN = fminf(MN, 0.0f);
        }
        comb[k]          = mean;
        comb[PK + k]     = MX;
        comb[2 * PK + k] = MN;
        comb[3 * PK + k] = sd;
    }
    __syncthreads();

    // Fused GEMV: out[m, o] = tanh(b[o] + sum_j comb[j] * W[j, o])
    if (t < PO) {
        const int o = t;
        float acc = b[o];
        #pragma unroll 8
        for (int j = 0; j < 4 * PK; ++j) {
            acc = fmaf(comb[j], W[(size_t)j * PO + o], acc);
        }
        out[(size_t)m * PO + o] = tanhf(acc);
    }
}

extern "C" void kernel_launch(void* const* d_in, const int* in_sizes, int n_in,
                              void* d_out, int out_size, void* d_ws, size_t ws_size,
                              hipStream_t stream) {
    const float* adj  = (const float*)d_in[0];
    const float* feat = (const float*)d_in[1];
    const float* W    = (const float*)d_in[2];
    const float* b    = (const float*)d_in[3];
    float* out = (float*)d_out;

    pna_fused_kernel<<<PM, 256, 0, stream>>>(adj, feat, W, b, out);
}